// Round 3
// baseline (17108.437 us; speedup 1.0000x reference)
//
#include <hip/hip_runtime.h>
#include <math.h>

#define BB 512
#define HH 512
#define SS 256
#define XD0 3
#define TDN 256
#define FC1N 20
#define OUTN 2
#define TM 32
#define TN 32
#define TK 32
#define NBLK 256   // persistent grid size

typedef __attribute__((ext_vector_type(8))) short short8;
typedef __attribute__((ext_vector_type(4))) short short4v;
typedef __attribute__((ext_vector_type(4))) float f32x4;

__device__ __forceinline__ unsigned short bf16_rne(float f) {
    unsigned u = __float_as_uint(f);
    u += 0x7FFFu + ((u >> 16) & 1u);
    return (unsigned short)(u >> 16);
}
__device__ __forceinline__ float bf16_to_f(unsigned short h) {
    return __uint_as_float(((unsigned)h) << 16);
}
__device__ __forceinline__ float sigmoid_(float x) { return 1.0f / (1.0f + __expf(-x)); }
__device__ __forceinline__ float tanh_(float x) {
    float e = __expf(2.0f * x);
    return 1.0f - 2.0f / (e + 1.0f);
}

// ---- weights fp32 [4H][H] -> MFMA B-frag layout [jt32][g4][kt16][lane64][e8], hi+lo split
__global__ __launch_bounds__(256)
void cvt_wfrag(const float* __restrict__ W, short* __restrict__ hi, short* __restrict__ lo)
{
    int idx = blockIdx.x * 256 + threadIdx.x;   // 0..131071
    int l   = idx & 63;
    int kt  = (idx >> 6) & 15;
    int g   = (idx >> 10) & 3;
    int jt  = idx >> 12;
    int row = g * HH + jt * 16 + (l & 15);
    int col = kt * 32 + (l >> 4) * 8;
    size_t src = (size_t)row * HH + col;
    size_t dst = (size_t)idx * 8;
    #pragma unroll
    for (int e = 0; e < 8; ++e) {
        float v = W[src + e];
        unsigned short h = bf16_rne(v);
        hi[dst + e] = (short)h;
        lo[dst + e] = (short)bf16_rne(v - bf16_to_f(h));
    }
}

// ---- initial h fp32 [r][k] -> A-frag layout [rt32][kt16][lane64][e8], hi+lo split
__global__ __launch_bounds__(256)
void cvt_hfrag(const float* __restrict__ Hsrc, short* __restrict__ hi, short* __restrict__ lo)
{
    int idx = blockIdx.x * 256 + threadIdx.x;   // 0..32767
    int l  = idx & 63;
    int kt = (idx >> 6) & 15;
    int rt = idx >> 10;
    int r = rt * 16 + (l & 15);
    int k = kt * 32 + (l >> 4) * 8;
    size_t src = (size_t)r * HH + k;
    size_t dst = (size_t)idx * 8;
    #pragma unroll
    for (int e = 0; e < 8; ++e) {
        float v = Hsrc[src + e];
        unsigned short h = bf16_rne(v);
        hi[dst + e] = (short)h;
        lo[dst + e] = (short)bf16_rne(v - bf16_to_f(h));
    }
}

__global__ void zero_sync(unsigned* s) { if (threadIdx.x < 4) s[threadIdx.x] = 0u; }

// device-scope grid barrier (all NBLK blocks guaranteed co-resident: 1 block/CU)
__device__ __forceinline__ void grid_barrier(unsigned* cnt, unsigned* gen, int p)
{
    __syncthreads();
    if (threadIdx.x == 0) {
        __threadfence();
        unsigned arrived = atomicAdd(cnt, 1u);
        if (arrived == (unsigned)(NBLK - 1)) {
            atomicExch(cnt, 0u);
            __threadfence();
            atomicExch(gen, (unsigned)(p + 1));
        } else {
            while (atomicAdd(gen, 0u) <= (unsigned)p) { __builtin_amdgcn_s_sleep(2); }
        }
        __threadfence();
    }
    __syncthreads();
}

// K-split(8) LDS tree reduction + fused LSTM cell epilogue.
// acc tiles: acc[rt][g], C-frag: row_local = rt*16 + (l>>4)*4 + q, col = l&15
template<int LAYER>
__device__ __forceinline__ void reduce_epilogue(
    f32x4 (&acc)[4][4], float (*quad)[4096],
    int kh, int l, int tid, int jt, int rblk, int p,
    const float* __restrict__ bih, const float* __restrict__ bhh,
    const float* __restrict__ cin, float* __restrict__ cst,
    short* __restrict__ hfh, short* __restrict__ hfl,
    float* __restrict__ Hf,
    const float* __restrict__ Wih0, const float* __restrict__ x)
{
    // round A: kh 4..7 -> quad[kh-4]
    if (kh >= 4) {
        #pragma unroll
        for (int rt = 0; rt < 4; ++rt)
            #pragma unroll
            for (int g = 0; g < 4; ++g)
                #pragma unroll
                for (int q = 0; q < 4; ++q)
                    quad[kh - 4][(g*64 + rt*16 + (l>>4)*4 + q)*16 + (l&15)] = acc[rt][g][q];
    }
    __syncthreads();
    // round B: kh 0..3 add quad[kh]
    if (kh < 4) {
        #pragma unroll
        for (int rt = 0; rt < 4; ++rt)
            #pragma unroll
            for (int g = 0; g < 4; ++g)
                #pragma unroll
                for (int q = 0; q < 4; ++q)
                    acc[rt][g][q] += quad[kh][(g*64 + rt*16 + (l>>4)*4 + q)*16 + (l&15)];
    }
    __syncthreads();
    if (kh == 2 || kh == 3) {
        #pragma unroll
        for (int rt = 0; rt < 4; ++rt)
            #pragma unroll
            for (int g = 0; g < 4; ++g)
                #pragma unroll
                for (int q = 0; q < 4; ++q)
                    quad[kh][(g*64 + rt*16 + (l>>4)*4 + q)*16 + (l&15)] = acc[rt][g][q];
    }
    __syncthreads();
    if (kh == 0 || kh == 1) {
        #pragma unroll
        for (int rt = 0; rt < 4; ++rt)
            #pragma unroll
            for (int g = 0; g < 4; ++g)
                #pragma unroll
                for (int q = 0; q < 4; ++q)
                    acc[rt][g][q] += quad[kh + 2][(g*64 + rt*16 + (l>>4)*4 + q)*16 + (l&15)];
        if (kh == 1) {
            #pragma unroll
            for (int rt = 0; rt < 4; ++rt)
                #pragma unroll
                for (int g = 0; g < 4; ++g)
                    #pragma unroll
                    for (int q = 0; q < 4; ++q)
                        quad[1][(g*64 + rt*16 + (l>>4)*4 + q)*16 + (l&15)] = acc[rt][g][q];
        }
    }
    __syncthreads();
    if (kh == 0) {
        #pragma unroll
        for (int rt = 0; rt < 4; ++rt)
            #pragma unroll
            for (int g = 0; g < 4; ++g) {
                #pragma unroll
                for (int q = 0; q < 4; ++q) {
                    acc[rt][g][q] += quad[1][(g*64 + rt*16 + (l>>4)*4 + q)*16 + (l&15)];
                    quad[0][(g*64 + rt*16 + (l>>4)*4 + q)*16 + (l&15)] = acc[rt][g][q];
                }
            }
    }
    __syncthreads();

    // epilogue: 256 threads, each (row, j-quad)
    if (tid < 256) {
        const int rl = tid >> 2;
        const int jl = (tid & 3) * 4;
        const int r  = rblk * 64 + rl;
        const int j  = jt * 16 + jl;
        f32x4 gv[4];
        #pragma unroll
        for (int g = 0; g < 4; ++g) {
            gv[g] = *(const f32x4*)&quad[0][(g*64 + rl)*16 + jl];
            f32x4 b1 = *(const f32x4*)&bih[g*HH + j];
            f32x4 b2 = *(const f32x4*)&bhh[g*HH + j];
            #pragma unroll
            for (int q = 0; q < 4; ++q) gv[g][q] += b1[q] + b2[q];
        }
        if (LAYER == 0) {
            const float x0 = x[(size_t)p * BB * XD0 + r * XD0 + 0];
            const float x1 = x[(size_t)p * BB * XD0 + r * XD0 + 1];
            const float x2 = x[(size_t)p * BB * XD0 + r * XD0 + 2];
            #pragma unroll
            for (int g = 0; g < 4; ++g)
                #pragma unroll
                for (int e = 0; e < 4; ++e) {
                    const float* wr_ = &Wih0[(size_t)(g*HH + j + e) * XD0];
                    gv[g][e] += x0 * wr_[0] + x1 * wr_[1] + x2 * wr_[2];
                }
        }
        f32x4 cv = *(const f32x4*)&cin[(size_t)r * HH + j];
        float hn[4];
        #pragma unroll
        for (int e = 0; e < 4; ++e) {
            float I = sigmoid_(gv[0][e]);
            float F = sigmoid_(gv[1][e]);
            float G = tanh_(gv[2][e]);
            float O = sigmoid_(gv[3][e]);
            float cn = F * cv[e] + I * G;
            cv[e] = cn;
            hn[e] = O * tanh_(cn);
        }
        *(f32x4*)&cst[(size_t)r * HH + j] = cv;
        // h -> A-frag layout (4 bf16 hi + 4 lo, 8B each)
        const int ktj   = j >> 5;
        const int lanew = (r & 15) | (((j & 31) >> 3) << 4);
        const int e0    = j & 7;      // 0 or 4
        const int rtg   = r >> 4;
        size_t hoff = ((((size_t)rtg)*16 + ktj)*64 + lanew)*8 + e0;
        short4v hhi, hlo;
        #pragma unroll
        for (int e = 0; e < 4; ++e) {
            unsigned short hb = bf16_rne(hn[e]);
            hhi[e] = (short)hb;
            hlo[e] = (short)bf16_rne(hn[e] - bf16_to_f(hb));
        }
        *(short4v*)&hfh[hoff] = hhi;
        *(short4v*)&hfl[hoff] = hlo;
        if (Hf != nullptr) {
            f32x4 hv;
            #pragma unroll
            for (int e = 0; e < 4; ++e) hv[e] = hn[e];
            *(f32x4*)&Hf[(size_t)r * HH + j] = hv;
        }
    }
    __syncthreads();   // protect quad reuse
}

__global__ __launch_bounds__(512, 2)
void lstm_persist(
    const short* __restrict__ W0h, const short* __restrict__ W0l,
    const short* __restrict__ W1h, const short* __restrict__ W1l,
    const short* __restrict__ WIh, const short* __restrict__ WIl,
    const float* __restrict__ Wih0, const float* __restrict__ x,
    const float* __restrict__ bih0, const float* __restrict__ bhh0,
    const float* __restrict__ bih1, const float* __restrict__ bhh1,
    const float* __restrict__ c0in,
    short* __restrict__ h0fh0, short* __restrict__ h0fl0,
    short* __restrict__ h0fh1, short* __restrict__ h0fl1,
    short* __restrict__ h1fh0, short* __restrict__ h1fl0,
    short* __restrict__ h1fh1, short* __restrict__ h1fl1,
    float* __restrict__ C0, float* __restrict__ C1,
    float* __restrict__ H0f, float* __restrict__ H1f,
    unsigned* __restrict__ sync)
{
    __shared__ float quad[4][4096];   // 64 KB

    const int tid  = threadIdx.x;
    const int kh   = tid >> 6;
    const int l    = tid & 63;
    const int bid  = blockIdx.x;
    const int jt   = bid & 31;        // XCD = bid%8 -> same-j weights per XCD
    const int rblk = bid >> 5;

    // persistent B_hi fragments (96 VGPRs)
    short8 b0h[2][4];
    short8 b1h[4][4];
    #pragma unroll
    for (int kk = 0; kk < 2; ++kk)
        #pragma unroll
        for (int g = 0; g < 4; ++g)
            b0h[kk][g] = *(const short8*)&W0h[((((size_t)jt*4 + g)*16 + (kh + kk*8))*64 + l)*8];
    #pragma unroll
    for (int kk = 0; kk < 4; ++kk)
        #pragma unroll
        for (int g = 0; g < 4; ++g) {
            const short* Wh = (kk < 2) ? W1h : WIh;
            const int kt = kh + (kk & 1) * 8;
            b1h[kk][g] = *(const short8*)&Wh[((((size_t)jt*4 + g)*16 + kt)*64 + l)*8];
        }

    for (int p = 0; p <= SS; ++p) {
        const int par = p & 1;
        // ---------------- layer 0, step p ----------------
        if (p < SS) {
            const short* Ah = par ? h0fh1 : h0fh0;
            const short* Al = par ? h0fl1 : h0fl0;
            f32x4 acc[4][4];
            #pragma unroll
            for (int rt = 0; rt < 4; ++rt)
                #pragma unroll
                for (int g = 0; g < 4; ++g)
                    #pragma unroll
                    for (int q = 0; q < 4; ++q) acc[rt][g][q] = 0.0f;
            #pragma unroll
            for (int kk = 0; kk < 2; ++kk) {
                const int kt = kh + kk * 8;
                short8 bl[4];
                #pragma unroll
                for (int g = 0; g < 4; ++g)
                    bl[g] = *(const short8*)&W0l[((((size_t)jt*4 + g)*16 + kt)*64 + l)*8];
                #pragma unroll
                for (int rt = 0; rt < 4; ++rt) {
                    const size_t ab = ((((size_t)(rblk*4 + rt))*16 + kt)*64 + l)*8;
                    short8 ah = *(const short8*)&Ah[ab];
                    short8 al = *(const short8*)&Al[ab];
                    #pragma unroll
                    for (int g = 0; g < 4; ++g) {
                        acc[rt][g] = __builtin_amdgcn_mfma_f32_16x16x32_bf16(ah, b0h[kk][g], acc[rt][g], 0,0,0);
                        acc[rt][g] = __builtin_amdgcn_mfma_f32_16x16x32_bf16(ah, bl[g],      acc[rt][g], 0,0,0);
                        acc[rt][g] = __builtin_amdgcn_mfma_f32_16x16x32_bf16(al, b0h[kk][g], acc[rt][g], 0,0,0);
                    }
                }
            }
            reduce_epilogue<0>(acc, quad, kh, l, tid, jt, rblk, p,
                               bih0, bhh0,
                               (p == 0) ? c0in : C0, C0,
                               par ? h0fh0 : h0fh1, par ? h0fl0 : h0fl1,
                               (p == SS - 1) ? H0f : nullptr, Wih0, x);
        }
        // ---------------- layer 1, step p-1 ----------------
        if (p >= 1) {
            const short* A1h = par ? h1fh1 : h1fh0;
            const short* A1l = par ? h1fl1 : h1fl0;
            const short* Y0h = par ? h0fh1 : h0fh0;
            const short* Y0l = par ? h0fl1 : h0fl0;
            f32x4 acc[4][4];
            #pragma unroll
            for (int rt = 0; rt < 4; ++rt)
                #pragma unroll
                for (int g = 0; g < 4; ++g)
                    #pragma unroll
                    for (int q = 0; q < 4; ++q) acc[rt][g][q] = 0.0f;
            #pragma unroll
            for (int kk = 0; kk < 4; ++kk) {
                const int kt = kh + (kk & 1) * 8;
                const short* Ah = (kk < 2) ? A1h : Y0h;
                const short* Al = (kk < 2) ? A1l : Y0l;
                const short* Wl = (kk < 2) ? W1l : WIl;
                short8 bl[4];
                #pragma unroll
                for (int g = 0; g < 4; ++g)
                    bl[g] = *(const short8*)&Wl[((((size_t)jt*4 + g)*16 + kt)*64 + l)*8];
                #pragma unroll
                for (int rt = 0; rt < 4; ++rt) {
                    const size_t ab = ((((size_t)(rblk*4 + rt))*16 + kt)*64 + l)*8;
                    short8 ah = *(const short8*)&Ah[ab];
                    short8 al = *(const short8*)&Al[ab];
                    #pragma unroll
                    for (int g = 0; g < 4; ++g) {
                        acc[rt][g] = __builtin_amdgcn_mfma_f32_16x16x32_bf16(ah, b1h[kk][g], acc[rt][g], 0,0,0);
                        acc[rt][g] = __builtin_amdgcn_mfma_f32_16x16x32_bf16(ah, bl[g],      acc[rt][g], 0,0,0);
                        acc[rt][g] = __builtin_amdgcn_mfma_f32_16x16x32_bf16(al, b1h[kk][g], acc[rt][g], 0,0,0);
                    }
                }
            }
            reduce_epilogue<1>(acc, quad, kh, l, tid, jt, rblk, p,
                               bih1, bhh1,
                               (p == 1) ? (c0in + (size_t)BB*HH) : C1, C1,
                               par ? h1fh0 : h1fh1, par ? h1fl0 : h1fl1,
                               (p == SS) ? H1f : nullptr, Wih0, x);
        }
        grid_barrier(&sync[0], &sync[1], p);
    }
}

// td[b][s] = btd[s] + cat(h0T,h1T)[b][:] . Wtd[s][:]  (validated R1/R2)
__global__ __launch_bounds__(256)
void td_kernel(const float* __restrict__ h0T, const float* __restrict__ h1T,
               const float* __restrict__ Wtd, const float* __restrict__ btd,
               float* __restrict__ td)
{
    __shared__ float a_lds[TM][TK + 1];
    __shared__ float b_lds[TN][TK + 1];
    const int t = threadIdx.x;
    const int nl = t & 31;
    const int mq = t >> 5;
    const int n0 = blockIdx.x * TN;
    const int m0 = blockIdx.y * TM;
    float acc[4] = {0.f, 0.f, 0.f, 0.f};

    for (int k0 = 0; k0 < 2 * HH; k0 += TK) {
        const float* src = (k0 < HH) ? h0T : h1T;
        int kb = k0 & (HH - 1);
        #pragma unroll
        for (int i = 0; i < (TM * TK) / 256; ++i) {
            int idx = t + i * 256;
            int r = idx >> 5, kk = idx & 31;
            a_lds[r][kk] = src[(size_t)(m0 + r) * HH + kb + kk];
        }
        #pragma unroll
        for (int i = 0; i < (TN * TK) / 256; ++i) {
            int idx = t + i * 256;
            int jn = idx >> 5, kk = idx & 31;
            b_lds[jn][kk] = Wtd[(size_t)(n0 + jn) * (2 * HH) + k0 + kk];
        }
        __syncthreads();
        #pragma unroll
        for (int kk = 0; kk < TK; ++kk) {
            float bv = b_lds[nl][kk];
            #pragma unroll
            for (int rr = 0; rr < 4; ++rr)
                acc[rr] = fmaf(a_lds[mq * 4 + rr][kk], bv, acc[rr]);
        }
        __syncthreads();
    }
    #pragma unroll
    for (int rr = 0; rr < 4; ++rr)
        td[(size_t)(m0 + mq * 4 + rr) * TDN + n0 + nl] = acc[rr] + btd[n0 + nl];
}

__global__ __launch_bounds__(256)
void fc_kernel(const float* __restrict__ td,
               const float* __restrict__ Wfc1, const float* __restrict__ bfc1,
               const float* __restrict__ Wfc2, const float* __restrict__ bfc2,
               float* __restrict__ out)
{
    __shared__ float td_lds[32][TDN];
    __shared__ float f1_lds[32][FC1N];
    const int t = threadIdx.x;
    const int r0 = blockIdx.x * 32;

    #pragma unroll
    for (int i = 0; i < (32 * TDN) / 256; ++i) {
        int idx = t + i * 256;
        int r = idx >> 8, k = idx & 255;
        td_lds[r][k] = td[(size_t)(r0 + r) * TDN + k];
    }
    __syncthreads();

    for (int idx = t; idx < 32 * FC1N; idx += 256) {
        int r = idx / FC1N, o = idx % FC1N;
        float s = bfc1[o];
        for (int k = 0; k < TDN; ++k) s = fmaf(td_lds[r][k], Wfc1[o * TDN + k], s);
        f1_lds[r][o] = fmaxf(s, 0.0f);
    }
    __syncthreads();

    for (int idx = t; idx < 32 * OUTN; idx += 256) {
        int r = idx / OUTN, o = idx % OUTN;
        float s = bfc2[o];
        for (int k = 0; k < FC1N; ++k) s = fmaf(f1_lds[r][k], Wfc2[o * FC1N + k], s);
        out[(size_t)(r0 + r) * OUTN + o] = s;
    }
}

extern "C" void kernel_launch(void* const* d_in, const int* in_sizes, int n_in,
                              void* d_out, int out_size, void* d_ws, size_t ws_size,
                              hipStream_t stream)
{
    const float* x    = (const float*)d_in[0];
    const float* h0   = (const float*)d_in[1];
    const float* c0   = (const float*)d_in[2];
    const float* Wih0 = (const float*)d_in[3];
    const float* Whh0 = (const float*)d_in[4];
    const float* bih0 = (const float*)d_in[5];
    const float* bhh0 = (const float*)d_in[6];
    const float* Wih1 = (const float*)d_in[7];
    const float* Whh1 = (const float*)d_in[8];
    const float* bih1 = (const float*)d_in[9];
    const float* bhh1 = (const float*)d_in[10];
    const float* Wtd  = (const float*)d_in[11];
    const float* btd  = (const float*)d_in[12];
    const float* Wfc1 = (const float*)d_in[13];
    const float* bfc1 = (const float*)d_in[14];
    const float* Wfc2 = (const float*)d_in[15];
    const float* bfc2 = (const float*)d_in[16];
    float* out = (float*)d_out;

    const size_t WSZ = (size_t)4 * HH * HH;      // 1M elems
    const size_t HFR = (size_t)32 * 16 * 64 * 8; // 262144 elems
    const size_t HSZ = (size_t)BB * HH;

    char* pp = (char*)d_ws;
    short* W0h = (short*)pp; pp += WSZ * 2;
    short* W0l = (short*)pp; pp += WSZ * 2;
    short* W1h = (short*)pp; pp += WSZ * 2;
    short* W1l = (short*)pp; pp += WSZ * 2;
    short* WIh = (short*)pp; pp += WSZ * 2;
    short* WIl = (short*)pp; pp += WSZ * 2;
    short* h0fh0 = (short*)pp; pp += HFR * 2;
    short* h0fl0 = (short*)pp; pp += HFR * 2;
    short* h0fh1 = (short*)pp; pp += HFR * 2;
    short* h0fl1 = (short*)pp; pp += HFR * 2;
    short* h1fh0 = (short*)pp; pp += HFR * 2;
    short* h1fl0 = (short*)pp; pp += HFR * 2;
    short* h1fh1 = (short*)pp; pp += HFR * 2;
    short* h1fl1 = (short*)pp; pp += HFR * 2;
    float* C0  = (float*)pp; pp += HSZ * 4;
    float* C1  = (float*)pp; pp += HSZ * 4;
    float* H0f = (float*)pp; pp += HSZ * 4;
    float* H1f = (float*)pp; pp += HSZ * 4;
    float* TD  = (float*)pp; pp += (size_t)BB * TDN * 4;
    unsigned* sync = (unsigned*)pp; pp += 64;

    // one-time (per call) weight/state conversion to fragment layouts
    cvt_wfrag<<<dim3(512), dim3(256), 0, stream>>>(Whh0, W0h, W0l);
    cvt_wfrag<<<dim3(512), dim3(256), 0, stream>>>(Whh1, W1h, W1l);
    cvt_wfrag<<<dim3(512), dim3(256), 0, stream>>>(Wih1, WIh, WIl);
    cvt_hfrag<<<dim3(128), dim3(256), 0, stream>>>(h0,        h0fh0, h0fl0);   // layer0 init -> parity 0
    cvt_hfrag<<<dim3(128), dim3(256), 0, stream>>>(h0 + HSZ,  h1fh1, h1fl1);   // layer1 init -> parity 1
    zero_sync<<<dim3(1), dim3(64), 0, stream>>>(sync);

    lstm_persist<<<dim3(NBLK), dim3(512), 0, stream>>>(
        W0h, W0l, W1h, W1l, WIh, WIl,
        Wih0, x, bih0, bhh0, bih1, bhh1, c0,
        h0fh0, h0fl0, h0fh1, h0fl1,
        h1fh0, h1fl0, h1fh1, h1fl1,
        C0, C1, H0f, H1f, sync);

    const dim3 gtd(TDN / TN, BB / TM);
    td_kernel<<<gtd, dim3(256), 0, stream>>>(H0f, H1f, Wtd, btd, TD);
    fc_kernel<<<dim3(BB / 32), dim3(256), 0, stream>>>(TD, Wfc1, bfc1, Wfc2, bfc2, out);

    (void)in_sizes; (void)n_in; (void)out_size; (void)ws_size;
}